// Round 3
// baseline (1573.659 us; speedup 1.0000x reference)
//
#include <hip/hip_runtime.h>
#include <math.h>

#define BB 8
#define CC 256
#define NTOK 2304   // 48*48
#define LOG2E 1.4426950408889634f
#define BIAS2 72.134752f   // ~50 * log2(e): logits*log2e max ~97*1.44, p=2^(s-BIAS2) overflow-free

typedef __attribute__((ext_vector_type(4))) float f32x4;
typedef __attribute__((ext_vector_type(2))) float f32x2;
typedef __attribute__((ext_vector_type(8))) short s16x8;
typedef __attribute__((ext_vector_type(4))) short s16x4;

__device__ inline unsigned short f2bf(float x) {
  unsigned u = __builtin_bit_cast(unsigned, x);
  return (unsigned short)((u + 0x7FFFu + ((u >> 16) & 1u)) >> 16);
}
__device__ inline float bf2f(unsigned short h) {
  return __builtin_bit_cast(float, (unsigned)h << 16);
}

// ---------------- projection ----------------
// Per batch: Y[n][d] = sum_c X[c][n] * W[d][c]   (fp32 accumulate)
// MODE 0: write Qh,Ql bf16 [n][d], scaled by LOG2E (split hi/lo)
// MODE 1: write Kh bf16 [n][d]
// MODE 2: write V^T bf16 [d][n]
template<int MODE>
__global__ __launch_bounds__(256)
void proj_kernel(const float* __restrict__ X, const float* __restrict__ W,
                 unsigned short* __restrict__ Y0, unsigned short* __restrict__ Y1) {
  const int n0 = blockIdx.x * 64;
  const int d0 = blockIdx.y * 64;
  const int b  = blockIdx.z;
  const float* Xb = X + (size_t)b * CC * NTOK;
  unsigned short* Yb0 = Y0 + (size_t)b * CC * NTOK;
  unsigned short* Yb1 = (MODE == 0) ? (Y1 + (size_t)b * CC * NTOK) : nullptr;

  __shared__ float Wt[32][68];   // Wt[c][d]
  __shared__ float Xs[32][68];   // Xs[c][n]

  const int t  = threadIdx.x;
  const int tn = t & 15;
  const int td = t >> 4;

  float acc[4][4];
  #pragma unroll
  for (int i = 0; i < 4; i++)
    #pragma unroll
    for (int j = 0; j < 4; j++) acc[i][j] = 0.f;

  for (int c0 = 0; c0 < CC; c0 += 32) {
    {
      const int c = t & 31, dr = t >> 5;
      #pragma unroll
      for (int j = 0; j < 8; j++) {
        int d = dr + 8 * j;
        Wt[c][d] = W[(size_t)(d0 + d) * CC + c0 + c];
      }
    }
    {
      const int n = t & 63, cr = t >> 6;
      #pragma unroll
      for (int j = 0; j < 8; j++) {
        int c = cr + 4 * j;
        Xs[c][n] = Xb[(size_t)(c0 + c) * NTOK + n0 + n];
      }
    }
    __syncthreads();
    #pragma unroll
    for (int c = 0; c < 32; c++) {
      float4 wv = *(const float4*)&Wt[c][td * 4];
      float4 xv = *(const float4*)&Xs[c][tn * 4];
      float wf[4] = {wv.x, wv.y, wv.z, wv.w};
      float xf[4] = {xv.x, xv.y, xv.z, xv.w};
      #pragma unroll
      for (int i = 0; i < 4; i++)
        #pragma unroll
        for (int j = 0; j < 4; j++)
          acc[i][j] = fmaf(xf[i], wf[j], acc[i][j]);
    }
    __syncthreads();
  }

  if (MODE == 0) {
    #pragma unroll
    for (int i = 0; i < 4; i++) {
      s16x4 hv, lv;
      #pragma unroll
      for (int j = 0; j < 4; j++) {
        float v = acc[i][j] * LOG2E;
        unsigned short h = f2bf(v);
        hv[j] = (short)h;
        lv[j] = (short)f2bf(v - bf2f(h));
      }
      int n = n0 + tn * 4 + i, d = d0 + td * 4;
      *(s16x4*)&Yb0[(size_t)n * CC + d] = hv;
      *(s16x4*)&Yb1[(size_t)n * CC + d] = lv;
    }
  } else if (MODE == 1) {
    #pragma unroll
    for (int i = 0; i < 4; i++) {
      s16x4 hv;
      #pragma unroll
      for (int j = 0; j < 4; j++) hv[j] = (short)f2bf(acc[i][j]);
      int n = n0 + tn * 4 + i, d = d0 + td * 4;
      *(s16x4*)&Yb0[(size_t)n * CC + d] = hv;
    }
  } else {
    #pragma unroll
    for (int j = 0; j < 4; j++) {
      s16x4 v;
      #pragma unroll
      for (int i = 0; i < 4; i++) v[i] = (short)f2bf(acc[i][j]);
      int d = d0 + td * 4 + j, n = n0 + tn * 4;
      *(s16x4*)&Yb0[(size_t)d * NTOK + n] = v;
    }
  }
}

// ---------------- fused dual-softmax MFMA attention, zero-barrier ----------------
// 1 wave per block. Wave owns 16 q-rows, BOTH paths, full 256-d output.
// K1/K2 [n][d] and Vt [d][n] fragments read DIRECTLY from global (L2-resident
// per XCD via b=bid&7 pinning). No __syncthreads anywhere.
__global__ __launch_bounds__(64)
void attn_kernel(const unsigned short* __restrict__ Qh, const unsigned short* __restrict__ Ql,
                 const unsigned short* __restrict__ K1, const unsigned short* __restrict__ K2,
                 const unsigned short* __restrict__ Vt, const float* __restrict__ qry,
                 const float* __restrict__ mup, float* __restrict__ out) {
  __shared__ float Pbuf[2][16][34];   // P transpose scratch (per-wave)
  __shared__ float Ws[16][68];        // epilogue transpose scratch (per-wave)

  const int l = threadIdx.x;
  const int g = l >> 4, c = l & 15;
  const int bid = blockIdx.x;
  const int b = bid & 7, rt = bid >> 3;     // batch -> XCD pinning; row-tile 0..143
  const int q0 = rt * 16;
  const size_t bo = (size_t)b * CC * NTOK;

  const char* Qhb = (const char*)(Qh + bo);
  const char* Qlb = (const char*)(Ql + bo);
  const char* K1b = (const char*)(K1 + bo);
  const char* K2b = (const char*)(K2 + bo);
  const char* Vtb = (const char*)(Vt + bo);

  // Q fragments resident (A-operand: lane(g,c) holds row q0+c, k-slice dc*32+g*8+0..7)
  s16x8 qh[8], ql[8];
  #pragma unroll
  for (int dc = 0; dc < 8; dc++) {
    int off = (q0 + c) * 512 + dc * 64 + g * 16;
    qh[dc] = *(const s16x8*)(Qhb + off);
    ql[dc] = *(const s16x8*)(Qlb + off);
  }

  f32x4 a1[16], a2[16];
  #pragma unroll
  for (int dt = 0; dt < 16; dt++) {
    a1[dt] = (f32x4){0.f, 0.f, 0.f, 0.f};
    a2[dt] = (f32x4){0.f, 0.f, 0.f, 0.f};
  }
  float lr1[4] = {0.f, 0.f, 0.f, 0.f};
  float lr2[4] = {0.f, 0.f, 0.f, 0.f};

  for (int k0 = 0; k0 < NTOK; k0 += 32) {
    // ---- S phase: B-frags straight from L2; p = 2^(s - BIAS2) (no-max softmax)
    #pragma unroll
    for (int p = 0; p < 2; p++) {
      const char* Kb = p ? K2b : K1b;
      float* lr = p ? lr2 : lr1;
      #pragma unroll
      for (int n = 0; n < 2; n++) {
        const int tok = k0 + n * 16 + c;
        f32x4 s = (f32x4){0.f, 0.f, 0.f, 0.f};
        #pragma unroll
        for (int dc = 0; dc < 8; dc++) {
          s16x8 kf = *(const s16x8*)(Kb + tok * 512 + dc * 64 + g * 16);
          s = __builtin_amdgcn_mfma_f32_16x16x32_bf16(qh[dc], kf, s, 0, 0, 0);
          s = __builtin_amdgcn_mfma_f32_16x16x32_bf16(ql[dc], kf, s, 0, 0, 0);
        }
        #pragma unroll
        for (int j = 0; j < 4; j++) {
          float pv = exp2f(s[j] - BIAS2);
          lr[j] += pv;
          Pbuf[p][g * 4 + j][n * 16 + c] = pv;   // row = q-row offset, col = tok
        }
      }
    }

    // ---- P -> bf16 A-fragments (wave-local LDS transpose)
    s16x8 pa[2];
    #pragma unroll
    for (int p = 0; p < 2; p++) {
      const float* Pr = &Pbuf[p][c][g * 8];
      s16x8 v;
      #pragma unroll
      for (int i = 0; i < 4; i++) {
        f32x2 pr = *(const f32x2*)(Pr + 2 * i);
        v[2 * i]     = (short)f2bf(pr[0]);
        v[2 * i + 1] = (short)f2bf(pr[1]);
      }
      pa[p] = v;
    }

    // ---- PV: V B-frags straight from L2 (shared by both paths)
    #pragma unroll
    for (int dt = 0; dt < 16; dt++) {
      s16x8 vf = *(const s16x8*)(Vtb + (dt * 16 + c) * 4608 + (k0 + g * 8) * 2);
      a1[dt] = __builtin_amdgcn_mfma_f32_16x16x32_bf16(pa[0], vf, a1[dt], 0, 0, 0);
      a2[dt] = __builtin_amdgcn_mfma_f32_16x16x32_bf16(pa[1], vf, a2[dt], 0, 0, 0);
    }
  }

  // ---- row-sum reduce across the 16 c-lanes of each g group
  #pragma unroll
  for (int j = 0; j < 4; j++) {
    #pragma unroll
    for (int off = 1; off < 16; off <<= 1) {
      lr1[j] += __shfl_xor(lr1[j], off);
      lr2[j] += __shfl_xor(lr2[j], off);
    }
  }
  const float mu = mup[0];
  const float cw1 = 0.5f / (0.5f + mu);
  const float cw2 = mu / (0.5f + mu);
  float r1[4], r2[4];
  #pragma unroll
  for (int j = 0; j < 4; j++) { r1[j] = cw1 / lr1[j]; r2[j] = cw2 / lr2[j]; }

  // ---- per-wave transposed epilogue in 64-col chunks: out[b][d][q] = qry + att
  const int q = l & 15, ds = l >> 4;
  #pragma unroll
  for (int ch = 0; ch < 4; ch++) {
    #pragma unroll
    for (int dtp = 0; dtp < 4; dtp++) {
      const int dt = ch * 4 + dtp;
      #pragma unroll
      for (int j = 0; j < 4; j++)
        Ws[g * 4 + j][dtp * 16 + c] = a1[dt][j] * r1[j] + a2[dt][j] * r2[j];
    }
    // wave-local write->read; compiler inserts lgkmcnt waits
    #pragma unroll
    for (int i = 0; i < 16; i++) {
      int d = ch * 64 + i * 4 + ds;
      size_t gi = bo + (size_t)d * NTOK + q0 + q;
      out[gi] = qry[gi] + Ws[q][i * 4 + ds];
    }
  }
}

extern "C" void kernel_launch(void* const* d_in, const int* in_sizes, int n_in,
                              void* d_out, int out_size, void* d_ws, size_t ws_size,
                              hipStream_t stream) {
  const float* qry  = (const float*)d_in[0];
  const float* mask = (const float*)d_in[1];
  const float* fts  = (const float*)d_in[2];
  const float* Wq   = (const float*)d_in[3];
  const float* Wk   = (const float*)d_in[4];
  const float* Wv   = (const float*)d_in[5];
  const float* mu   = (const float*)d_in[6];
  float* out = (float*)d_out;

  const size_t SZ = (size_t)BB * CC * NTOK;
  unsigned short* Qhw = (unsigned short*)d_ws;
  unsigned short* Qlw = Qhw + SZ;
  unsigned short* K1w = Qhw + 2 * SZ;
  unsigned short* K2w = Qhw + 3 * SZ;
  unsigned short* Vtw = Qhw + 4 * SZ;

  dim3 pg(NTOK / 64, CC / 64, BB);
  proj_kernel<0><<<pg, 256, 0, stream>>>(qry,  Wq, Qhw, Qlw);
  proj_kernel<1><<<pg, 256, 0, stream>>>(fts,  Wk, K1w, nullptr);
  proj_kernel<1><<<pg, 256, 0, stream>>>(mask, Wk, K2w, nullptr);
  proj_kernel<2><<<pg, 256, 0, stream>>>(fts,  Wv, Vtw, nullptr);

  attn_kernel<<<BB * (NTOK / 16), 64, 0, stream>>>(Qhw, Qlw, K1w, K2w, Vtw, qry, mu, out);
}

// Round 4
// 877.740 us; speedup vs baseline: 1.7929x; 1.7929x over previous
//
#include <hip/hip_runtime.h>
#include <math.h>

#define BB 8
#define CC 256
#define NTOK 2304   // 48*48
#define LOG2E 1.4426950408889634f
#define BIAS2 72.134752f   // ~50*log2(e): p = 2^(s-BIAS2), overflow-free, no-max softmax

typedef __attribute__((ext_vector_type(4))) float f32x4;
typedef __attribute__((ext_vector_type(2))) float f32x2;
typedef __attribute__((ext_vector_type(8))) short s16x8;
typedef __attribute__((ext_vector_type(4))) short s16x4;

__device__ inline unsigned short f2bf(float x) {
  unsigned u = __builtin_bit_cast(unsigned, x);
  return (unsigned short)((u + 0x7FFFu + ((u >> 16) & 1u)) >> 16);
}
__device__ inline float bf2f(unsigned short h) {
  return __builtin_bit_cast(float, (unsigned)h << 16);
}

// ---------------- projection ----------------
// Per batch: Y[n][d] = sum_c X[c][n] * W[d][c]   (fp32 accumulate)
// MODE 0: write Qh,Ql bf16 [n][d], scaled by LOG2E (split hi/lo)
// MODE 1: write Kh bf16 [n][d]
// MODE 2: write V^T bf16 [d][n]
template<int MODE>
__global__ __launch_bounds__(256)
void proj_kernel(const float* __restrict__ X, const float* __restrict__ W,
                 unsigned short* __restrict__ Y0, unsigned short* __restrict__ Y1) {
  const int n0 = blockIdx.x * 64;
  const int d0 = blockIdx.y * 64;
  const int b  = blockIdx.z;
  const float* Xb = X + (size_t)b * CC * NTOK;
  unsigned short* Yb0 = Y0 + (size_t)b * CC * NTOK;
  unsigned short* Yb1 = (MODE == 0) ? (Y1 + (size_t)b * CC * NTOK) : nullptr;

  __shared__ float Wt[32][68];   // Wt[c][d]
  __shared__ float Xs[32][68];   // Xs[c][n]

  const int t  = threadIdx.x;
  const int tn = t & 15;
  const int td = t >> 4;

  float acc[4][4];
  #pragma unroll
  for (int i = 0; i < 4; i++)
    #pragma unroll
    for (int j = 0; j < 4; j++) acc[i][j] = 0.f;

  for (int c0 = 0; c0 < CC; c0 += 32) {
    {
      const int c = t & 31, dr = t >> 5;
      #pragma unroll
      for (int j = 0; j < 8; j++) {
        int d = dr + 8 * j;
        Wt[c][d] = W[(size_t)(d0 + d) * CC + c0 + c];
      }
    }
    {
      const int n = t & 63, cr = t >> 6;
      #pragma unroll
      for (int j = 0; j < 8; j++) {
        int c = cr + 4 * j;
        Xs[c][n] = Xb[(size_t)(c0 + c) * NTOK + n0 + n];
      }
    }
    __syncthreads();
    #pragma unroll
    for (int c = 0; c < 32; c++) {
      float4 wv = *(const float4*)&Wt[c][td * 4];
      float4 xv = *(const float4*)&Xs[c][tn * 4];
      float wf[4] = {wv.x, wv.y, wv.z, wv.w};
      float xf[4] = {xv.x, xv.y, xv.z, xv.w};
      #pragma unroll
      for (int i = 0; i < 4; i++)
        #pragma unroll
        for (int j = 0; j < 4; j++)
          acc[i][j] = fmaf(xf[i], wf[j], acc[i][j]);
    }
    __syncthreads();
  }

  if (MODE == 0) {
    #pragma unroll
    for (int i = 0; i < 4; i++) {
      s16x4 hv, lv;
      #pragma unroll
      for (int j = 0; j < 4; j++) {
        float v = acc[i][j] * LOG2E;
        unsigned short h = f2bf(v);
        hv[j] = (short)h;
        lv[j] = (short)f2bf(v - bf2f(h));
      }
      int n = n0 + tn * 4 + i, d = d0 + td * 4;
      *(s16x4*)&Yb0[(size_t)n * CC + d] = hv;
      *(s16x4*)&Yb1[(size_t)n * CC + d] = lv;
    }
  } else if (MODE == 1) {
    #pragma unroll
    for (int i = 0; i < 4; i++) {
      s16x4 hv;
      #pragma unroll
      for (int j = 0; j < 4; j++) hv[j] = (short)f2bf(acc[i][j]);
      int n = n0 + tn * 4 + i, d = d0 + td * 4;
      *(s16x4*)&Yb0[(size_t)n * CC + d] = hv;
    }
  } else {
    #pragma unroll
    for (int j = 0; j < 4; j++) {
      s16x4 v;
      #pragma unroll
      for (int i = 0; i < 4; i++) v[i] = (short)f2bf(acc[i][j]);
      int d = d0 + td * 4 + j, n = n0 + tn * 4;
      *(s16x4*)&Yb0[(size_t)d * NTOK + n] = v;
    }
  }
}

// ---------------- fused dual-softmax MFMA attention, k-split ----------------
// 8 waves/block (512 thr): 2 q-subtiles x 4 k-quarters. Each wave: 16 q-rows,
// both paths, 18 k-tiles of 32 toks, B-frags straight from L2 (b=bid&7 XCD pin).
// No-max softmax => k-split partials (a,l) sum linearly; barrier-ordered LDS
// combine rounds (deterministic), then transposed residual epilogue.
__global__ __launch_bounds__(512, 1)
void attn_kernel(const unsigned short* __restrict__ Qh, const unsigned short* __restrict__ Ql,
                 const unsigned short* __restrict__ K1, const unsigned short* __restrict__ K2,
                 const unsigned short* __restrict__ Vt, const float* __restrict__ qry,
                 const float* __restrict__ mup, float* __restrict__ out) {
  __shared__ float Pbuf[8][2][16][34];     // per-wave P transpose scratch
  __shared__ float accs[2][16][257];       // per-qsub k-split accumulation
  __shared__ float att[32][257];           // combined output tile
  __shared__ float lbuf[2][2][4][16];      // [path][qsub][wk][row] partial l

  const int t = threadIdx.x;
  const int w = t >> 6, l = t & 63, g = l >> 4, c = l & 15;
  const int qsub = w >> 2, wk = w & 3;
  const int bid = blockIdx.x;
  const int b = bid & 7, rt = bid >> 3;    // batch -> XCD pin; row-tile 0..71
  const int q0 = rt * 32 + qsub * 16;
  const size_t bo = (size_t)b * CC * NTOK;

  const char* Qhb = (const char*)(Qh + bo);
  const char* Qlb = (const char*)(Ql + bo);
  const char* K1b = (const char*)(K1 + bo);
  const char* K2b = (const char*)(K2 + bo);
  const char* Vtb = (const char*)(Vt + bo);

  // Q fragments resident (A-operand: lane(g,c) holds row q0+c, k-slice dc*32+g*8+0..7)
  s16x8 qh[8], ql[8];
  #pragma unroll
  for (int dc = 0; dc < 8; dc++) {
    int off = (q0 + c) * 512 + dc * 64 + g * 16;
    qh[dc] = *(const s16x8*)(Qhb + off);
    ql[dc] = *(const s16x8*)(Qlb + off);
  }

  f32x4 a1[16], a2[16];
  #pragma unroll
  for (int dt = 0; dt < 16; dt++) {
    a1[dt] = (f32x4){0.f, 0.f, 0.f, 0.f};
    a2[dt] = (f32x4){0.f, 0.f, 0.f, 0.f};
  }
  float lr1[4] = {0.f, 0.f, 0.f, 0.f};
  float lr2[4] = {0.f, 0.f, 0.f, 0.f};

  for (int kt = 0; kt < 18; kt++) {
    const int k0 = wk * 576 + kt * 32;
    // ---- S phase: K B-frags straight from L2; p = 2^(s - BIAS2)
    #pragma unroll
    for (int p = 0; p < 2; p++) {
      const char* Kb = p ? K2b : K1b;
      float* lr = p ? lr2 : lr1;
      #pragma unroll
      for (int n = 0; n < 2; n++) {
        const int tok = k0 + n * 16 + c;
        f32x4 s = (f32x4){0.f, 0.f, 0.f, 0.f};
        #pragma unroll
        for (int dc = 0; dc < 8; dc++) {
          s16x8 kf = *(const s16x8*)(Kb + tok * 512 + dc * 64 + g * 16);
          s = __builtin_amdgcn_mfma_f32_16x16x32_bf16(qh[dc], kf, s, 0, 0, 0);
          s = __builtin_amdgcn_mfma_f32_16x16x32_bf16(ql[dc], kf, s, 0, 0, 0);
        }
        #pragma unroll
        for (int j = 0; j < 4; j++) {
          float pv = exp2f(s[j] - BIAS2);
          lr[j] += pv;
          Pbuf[w][p][g * 4 + j][n * 16 + c] = pv;   // row = q-row offset, col = tok
        }
      }
    }

    // ---- P -> bf16 A-fragments (wave-local LDS transpose)
    s16x8 pa[2];
    #pragma unroll
    for (int p = 0; p < 2; p++) {
      const float* Pr = &Pbuf[w][p][c][g * 8];
      s16x8 v;
      #pragma unroll
      for (int i = 0; i < 4; i++) {
        f32x2 pr = *(const f32x2*)(Pr + 2 * i);
        v[2 * i]     = (short)f2bf(pr[0]);
        v[2 * i + 1] = (short)f2bf(pr[1]);
      }
      pa[p] = v;
    }

    // ---- PV: V B-frags straight from L2 (shared by both paths)
    #pragma unroll
    for (int dt = 0; dt < 16; dt++) {
      s16x8 vf = *(const s16x8*)(Vtb + (dt * 16 + c) * 4608 + (k0 + g * 8) * 2);
      a1[dt] = __builtin_amdgcn_mfma_f32_16x16x32_bf16(pa[0], vf, a1[dt], 0, 0, 0);
      a2[dt] = __builtin_amdgcn_mfma_f32_16x16x32_bf16(pa[1], vf, a2[dt], 0, 0, 0);
    }
  }

  // ---- partial row sums: reduce across the 16 c-lanes of each g group
  #pragma unroll
  for (int j = 0; j < 4; j++) {
    #pragma unroll
    for (int off = 1; off < 16; off <<= 1) {
      lr1[j] += __shfl_xor(lr1[j], off);
      lr2[j] += __shfl_xor(lr2[j], off);
    }
  }
  if (c == 0) {
    #pragma unroll
    for (int j = 0; j < 4; j++) {
      lbuf[0][qsub][wk][g * 4 + j] = lr1[j];
      lbuf[1][qsub][wk][g * 4 + j] = lr2[j];
    }
  }
  __syncthreads();

  const float mu = mup[0];
  const float cw1 = 0.5f / (0.5f + mu);
  const float cw2 = mu / (0.5f + mu);

  // ---- barrier-ordered k-split combine (deterministic), per path
  #pragma unroll
  for (int p = 0; p < 2; p++) {
    const f32x4* ap = p ? a2 : a1;
    for (int r = 0; r < 4; r++) {
      if (wk == r) {
        #pragma unroll
        for (int dt = 0; dt < 16; dt++) {
          #pragma unroll
          for (int j = 0; j < 4; j++) {
            float* cell = &accs[qsub][g * 4 + j][dt * 16 + c];
            if (r == 0) *cell = ap[dt][j];
            else        *cell += ap[dt][j];
          }
        }
      }
      __syncthreads();
    }
    // scale by combined 1/l and blend into att (all 512 threads)
    {
      const int q = t & 31, dbase = t >> 5;
      const int qs = q >> 4, qr = q & 15;
      float lt = lbuf[p][qs][0][qr] + lbuf[p][qs][1][qr] +
                 lbuf[p][qs][2][qr] + lbuf[p][qs][3][qr];
      float rp = (p ? cw2 : cw1) / lt;
      #pragma unroll
      for (int i = 0; i < 16; i++) {
        int d = dbase * 16 + i;
        float v = accs[qs][qr][d] * rp;
        if (p == 0) att[q][d] = v;
        else        att[q][d] += v;
      }
    }
    __syncthreads();
  }

  // ---- transposed residual epilogue: out[b][d][rt*32 + q] = qry + att
  const int q = t & 31, dbase = t >> 5;
  const int qg = rt * 32;
  #pragma unroll
  for (int i = 0; i < 16; i++) {
    int d = dbase + 16 * i;
    size_t gi = bo + (size_t)d * NTOK + qg + q;
    out[gi] = qry[gi] + att[q][d];
  }
}

extern "C" void kernel_launch(void* const* d_in, const int* in_sizes, int n_in,
                              void* d_out, int out_size, void* d_ws, size_t ws_size,
                              hipStream_t stream) {
  const float* qry  = (const float*)d_in[0];
  const float* mask = (const float*)d_in[1];
  const float* fts  = (const float*)d_in[2];
  const float* Wq   = (const float*)d_in[3];
  const float* Wk   = (const float*)d_in[4];
  const float* Wv   = (const float*)d_in[5];
  const float* mu   = (const float*)d_in[6];
  float* out = (float*)d_out;

  const size_t SZ = (size_t)BB * CC * NTOK;
  unsigned short* Qhw = (unsigned short*)d_ws;
  unsigned short* Qlw = Qhw + SZ;
  unsigned short* K1w = Qhw + 2 * SZ;
  unsigned short* K2w = Qhw + 3 * SZ;
  unsigned short* Vtw = Qhw + 4 * SZ;

  dim3 pg(NTOK / 64, CC / 64, BB);
  proj_kernel<0><<<pg, 256, 0, stream>>>(qry,  Wq, Qhw, Qlw);
  proj_kernel<1><<<pg, 256, 0, stream>>>(fts,  Wk, K1w, nullptr);
  proj_kernel<1><<<pg, 256, 0, stream>>>(mask, Wk, K2w, nullptr);
  proj_kernel<2><<<pg, 256, 0, stream>>>(fts,  Wv, Vtw, nullptr);

  attn_kernel<<<BB * (NTOK / 32), 512, 0, stream>>>(Qhw, Qlw, K1w, K2w, Vtw, qry, mu, out);
}

// Round 5
// 569.093 us; speedup vs baseline: 2.7652x; 1.5423x over previous
//
#include <hip/hip_runtime.h>
#include <math.h>

#define BB 8
#define CC 256
#define NTOK 2304   // 48*48
#define LOG2E 1.4426950408889634f
#define BIAS2 72.134752f   // ~50*log2(e): p = 2^(s-BIAS2), overflow-free, no-max softmax

typedef __attribute__((ext_vector_type(4))) float f32x4;
typedef __attribute__((ext_vector_type(2))) float f32x2;
typedef __attribute__((ext_vector_type(8))) short s16x8;
typedef __attribute__((ext_vector_type(4))) short s16x4;

__device__ inline unsigned short f2bf(float x) {
  unsigned u = __builtin_bit_cast(unsigned, x);
  return (unsigned short)((u + 0x7FFFu + ((u >> 16) & 1u)) >> 16);
}
__device__ inline float bf2f(unsigned short h) {
  return __builtin_bit_cast(float, (unsigned)h << 16);
}

// async global -> LDS, 16B per lane, zero VGPR round-trip
__device__ inline void async16(void* lds, const void* g) {
  __builtin_amdgcn_global_load_lds(
      (const __attribute__((address_space(1))) unsigned int*)g,
      (__attribute__((address_space(3))) unsigned int*)lds, 16, 0, 0);
}

// ---------------- projection ----------------
// Per batch: Y[n][d] = sum_c X[c][n] * W[d][c]   (fp32 accumulate)
// MODE 0: write Qh,Ql bf16 [n][d], scaled by LOG2E (split hi/lo)
// MODE 1: write Kh bf16 [n][d]
// MODE 2: write V^T bf16 [d][n]
template<int MODE>
__global__ __launch_bounds__(256)
void proj_kernel(const float* __restrict__ X, const float* __restrict__ W,
                 unsigned short* __restrict__ Y0, unsigned short* __restrict__ Y1) {
  const int n0 = blockIdx.x * 64;
  const int d0 = blockIdx.y * 64;
  const int b  = blockIdx.z;
  const float* Xb = X + (size_t)b * CC * NTOK;
  unsigned short* Yb0 = Y0 + (size_t)b * CC * NTOK;
  unsigned short* Yb1 = (MODE == 0) ? (Y1 + (size_t)b * CC * NTOK) : nullptr;

  __shared__ float Wt[32][68];   // Wt[c][d]
  __shared__ float Xs[32][68];   // Xs[c][n]

  const int t  = threadIdx.x;
  const int tn = t & 15;
  const int td = t >> 4;

  float acc[4][4];
  #pragma unroll
  for (int i = 0; i < 4; i++)
    #pragma unroll
    for (int j = 0; j < 4; j++) acc[i][j] = 0.f;

  for (int c0 = 0; c0 < CC; c0 += 32) {
    {
      const int c = t & 31, dr = t >> 5;
      #pragma unroll
      for (int j = 0; j < 8; j++) {
        int d = dr + 8 * j;
        Wt[c][d] = W[(size_t)(d0 + d) * CC + c0 + c];
      }
    }
    {
      const int n = t & 63, cr = t >> 6;
      #pragma unroll
      for (int j = 0; j < 8; j++) {
        int c = cr + 4 * j;
        Xs[c][n] = Xb[(size_t)(c0 + c) * NTOK + n0 + n];
      }
    }
    __syncthreads();
    #pragma unroll
    for (int c = 0; c < 32; c++) {
      float4 wv = *(const float4*)&Wt[c][td * 4];
      float4 xv = *(const float4*)&Xs[c][tn * 4];
      float wf[4] = {wv.x, wv.y, wv.z, wv.w};
      float xf[4] = {xv.x, xv.y, xv.z, xv.w};
      #pragma unroll
      for (int i = 0; i < 4; i++)
        #pragma unroll
        for (int j = 0; j < 4; j++)
          acc[i][j] = fmaf(xf[i], wf[j], acc[i][j]);
    }
    __syncthreads();
  }

  if (MODE == 0) {
    #pragma unroll
    for (int i = 0; i < 4; i++) {
      s16x4 hv, lv;
      #pragma unroll
      for (int j = 0; j < 4; j++) {
        float v = acc[i][j] * LOG2E;
        unsigned short h = f2bf(v);
        hv[j] = (short)h;
        lv[j] = (short)f2bf(v - bf2f(h));
      }
      int n = n0 + tn * 4 + i, d = d0 + td * 4;
      *(s16x4*)&Yb0[(size_t)n * CC + d] = hv;
      *(s16x4*)&Yb1[(size_t)n * CC + d] = lv;
    }
  } else if (MODE == 1) {
    #pragma unroll
    for (int i = 0; i < 4; i++) {
      s16x4 hv;
      #pragma unroll
      for (int j = 0; j < 4; j++) hv[j] = (short)f2bf(acc[i][j]);
      int n = n0 + tn * 4 + i, d = d0 + td * 4;
      *(s16x4*)&Yb0[(size_t)n * CC + d] = hv;
    }
  } else {
    #pragma unroll
    for (int j = 0; j < 4; j++) {
      s16x4 v;
      #pragma unroll
      for (int i = 0; i < 4; i++) v[i] = (short)f2bf(acc[i][j]);
      int d = d0 + td * 4 + j, n = n0 + tn * 4;
      *(s16x4*)&Yb0[(size_t)d * NTOK + n] = v;
    }
  }
}

// ---------------- fused dual-softmax MFMA attention, gload_lds-staged ----------------
// 4 waves/block, 64 q-rows (16/wave), KVB=32. Per k-tile: stage K1,K2 (row-XOR
// pre-swizzled source) + V^T into LDS via global_load_lds (no VGPR cost), then
// MFMA from LDS. b=bid&7 pins batch -> XCD (K/V L2-resident, 3.5MB/XCD).
__global__ __launch_bounds__(256, 2)
void attn_kernel(const unsigned short* __restrict__ Qh, const unsigned short* __restrict__ Ql,
                 const unsigned short* __restrict__ K1, const unsigned short* __restrict__ K2,
                 const unsigned short* __restrict__ Vt, const float* __restrict__ qry,
                 const float* __restrict__ mup, float* __restrict__ out) {
  // [0,16K) K1s | [16K,32K) K2s | [32K,48K) Vs | [48K, 48K+4*4352) per-wave P/Ws
  __shared__ alignas(16) char smem[66560];
  const int VO = 32768, PO = 49152;

  const int t = threadIdx.x;
  const int w = t >> 6, l = t & 63, g = l >> 4, c = l & 15;
  const int bid = blockIdx.x;
  const int b = bid & 7, qt = bid >> 3;     // batch -> XCD pin; q-tile 0..35
  const int q0 = qt * 64 + w * 16;          // this wave's 16 q-rows
  const size_t bo = (size_t)b * CC * NTOK;

  const char* Qhb = (const char*)(Qh + bo);
  const char* Qlb = (const char*)(Ql + bo);
  const char* K1b = (const char*)(K1 + bo);
  const char* K2b = (const char*)(K2 + bo);
  const char* Vtb = (const char*)(Vt + bo);

  // ---- staging descriptors: 48 chunks of 1KB; wave w takes chunk w+4i.
  // i 0..3 -> K1, 4..7 -> K2, 8..11 -> V (kind static after unroll).
  // K source pre-swizzled: col ^ ((tok&7)<<4); V: col ^ (((row>>2)&3)<<4).
  const char* gsrc[12];
  #pragma unroll
  for (int i = 0; i < 12; i++) {
    if (i < 8) {
      int ck = w + 4 * (i & 3);            // chunk within region, 0..15
      int tok = ck * 2 + (l >> 5);         // 0..31
      int col = (l & 31) * 16;
      int src = tok * 512 + (col ^ ((tok & 7) << 4));
      gsrc[i] = (i < 4 ? K1b : K2b) + src;
    } else {
      int ck = w + 4 * (i - 8);            // 0..15
      int row = ck * 16 + (l >> 2);        // 0..255
      int col = (l & 3) * 16;
      int src = row * 4608 + (col ^ (((l >> 4) & 3) << 4));
      gsrc[i] = Vtb + src;
    }
  }

  // per-lane constant read offsets (swizzles collapse to lane constants)
  int kxor[8];
  #pragma unroll
  for (int dc = 0; dc < 8; dc++)
    kxor[dc] = (dc * 64 + g * 16) ^ ((c & 7) << 4);
  const int gxv = (g * 16) ^ (((c >> 2) & 3) << 4);

  // Q fragments resident (A-operand: lane(g,c) holds row q0+c, k-slice dc*32+g*8+0..7)
  s16x8 qh[8], ql[8];
  #pragma unroll
  for (int dc = 0; dc < 8; dc++) {
    int off = (q0 + c) * 512 + dc * 64 + g * 16;
    qh[dc] = *(const s16x8*)(Qhb + off);
    ql[dc] = *(const s16x8*)(Qlb + off);
  }

  f32x4 a1[16], a2[16];
  #pragma unroll
  for (int dt = 0; dt < 16; dt++) {
    a1[dt] = (f32x4){0.f, 0.f, 0.f, 0.f};
    a2[dt] = (f32x4){0.f, 0.f, 0.f, 0.f};
  }
  float lr1[4] = {0.f, 0.f, 0.f, 0.f};
  float lr2[4] = {0.f, 0.f, 0.f, 0.f};

  char* const Pw = smem + PO + w * 4352;   // per-wave [2][16][34] f32 scratch

  for (int kt = 0; kt < NTOK / 32; kt++) {
    __syncthreads();                        // all waves done reading prev tile
    {
      char* ldsb = smem + w * 1024;
      #pragma unroll
      for (int i = 0; i < 12; i++) {
        async16(ldsb + i * 4096, gsrc[i]);
        gsrc[i] += (i < 8) ? 32 * 512 : 64;
      }
    }
    __syncthreads();                        // compiler drains vmcnt before barrier

    // ---- S phase: K frags from LDS (swizzled); p = 2^(s - BIAS2)
    #pragma unroll
    for (int p = 0; p < 2; p++) {
      const char* Kp = smem + p * 16384;
      float* lr = p ? lr2 : lr1;
      #pragma unroll
      for (int n = 0; n < 2; n++) {
        f32x4 s = (f32x4){0.f, 0.f, 0.f, 0.f};
        const char* Kt = Kp + (n * 16 + c) * 512;
        #pragma unroll
        for (int dc = 0; dc < 8; dc++) {
          s16x8 kf = *(const s16x8*)(Kt + kxor[dc]);
          s = __builtin_amdgcn_mfma_f32_16x16x32_bf16(qh[dc], kf, s, 0, 0, 0);
          s = __builtin_amdgcn_mfma_f32_16x16x32_bf16(ql[dc], kf, s, 0, 0, 0);
        }
        #pragma unroll
        for (int j = 0; j < 4; j++) {
          float pv = exp2f(s[j] - BIAS2);
          lr[j] += pv;
          *(float*)(Pw + (((p * 16) + g * 4 + j) * 34 + n * 16 + c) * 4) = pv;
        }
      }
    }

    // ---- P -> bf16 A-fragments (wave-local LDS transpose)
    s16x8 pa[2];
    #pragma unroll
    for (int p = 0; p < 2; p++) {
      const char* Pr = Pw + (p * 16 + c) * 136 + g * 32;
      s16x8 v;
      #pragma unroll
      for (int i = 0; i < 4; i++) {
        f32x2 pr = *(const f32x2*)(Pr + 8 * i);
        v[2 * i]     = (short)f2bf(pr[0]);
        v[2 * i + 1] = (short)f2bf(pr[1]);
      }
      pa[p] = v;
    }

    // ---- PV: V frags from LDS (shared by both paths)
    #pragma unroll
    for (int dt = 0; dt < 16; dt++) {
      s16x8 vf = *(const s16x8*)(smem + VO + (dt * 16 + c) * 64 + gxv);
      a1[dt] = __builtin_amdgcn_mfma_f32_16x16x32_bf16(pa[0], vf, a1[dt], 0, 0, 0);
      a2[dt] = __builtin_amdgcn_mfma_f32_16x16x32_bf16(pa[1], vf, a2[dt], 0, 0, 0);
    }
  }

  // ---- row-sum reduce across the 16 c-lanes of each g group
  #pragma unroll
  for (int j = 0; j < 4; j++) {
    #pragma unroll
    for (int off = 1; off < 16; off <<= 1) {
      lr1[j] += __shfl_xor(lr1[j], off);
      lr2[j] += __shfl_xor(lr2[j], off);
    }
  }
  const float mu = mup[0];
  const float cw1 = 0.5f / (0.5f + mu);
  const float cw2 = mu / (0.5f + mu);
  float r1[4], r2[4];
  #pragma unroll
  for (int j = 0; j < 4; j++) { r1[j] = cw1 / lr1[j]; r2[j] = cw2 / lr2[j]; }

  // ---- per-wave transposed epilogue (wave-private Ws = Pw region, [16][68] f32)
  float* Ws = (float*)Pw;
  const int q = l & 15, ds = l >> 4;
  #pragma unroll
  for (int ch = 0; ch < 4; ch++) {
    #pragma unroll
    for (int dtp = 0; dtp < 4; dtp++) {
      const int dt = ch * 4 + dtp;
      #pragma unroll
      for (int j = 0; j < 4; j++)
        Ws[(g * 4 + j) * 68 + dtp * 16 + c] = a1[dt][j] * r1[j] + a2[dt][j] * r2[j];
    }
    // wave-local write->read; compiler inserts lgkmcnt waits
    #pragma unroll
    for (int i = 0; i < 16; i++) {
      int d = ch * 64 + i * 4 + ds;
      size_t gi = bo + (size_t)d * NTOK + q0 + q;
      out[gi] = qry[gi] + Ws[q * 68 + i * 4 + ds];
    }
  }
}

extern "C" void kernel_launch(void* const* d_in, const int* in_sizes, int n_in,
                              void* d_out, int out_size, void* d_ws, size_t ws_size,
                              hipStream_t stream) {
  const float* qry  = (const float*)d_in[0];
  const float* mask = (const float*)d_in[1];
  const float* fts  = (const float*)d_in[2];
  const float* Wq   = (const float*)d_in[3];
  const float* Wk   = (const float*)d_in[4];
  const float* Wv   = (const float*)d_in[5];
  const float* mu   = (const float*)d_in[6];
  float* out = (float*)d_out;

  const size_t SZ = (size_t)BB * CC * NTOK;
  unsigned short* Qhw = (unsigned short*)d_ws;
  unsigned short* Qlw = Qhw + SZ;
  unsigned short* K1w = Qhw + 2 * SZ;
  unsigned short* K2w = Qhw + 3 * SZ;
  unsigned short* Vtw = Qhw + 4 * SZ;

  dim3 pg(NTOK / 64, CC / 64, BB);
  proj_kernel<0><<<pg, 256, 0, stream>>>(qry,  Wq, Qhw, Qlw);
  proj_kernel<1><<<pg, 256, 0, stream>>>(fts,  Wk, K1w, nullptr);
  proj_kernel<1><<<pg, 256, 0, stream>>>(mask, Wk, K2w, nullptr);
  proj_kernel<2><<<pg, 256, 0, stream>>>(fts,  Wv, Vtw, nullptr);

  attn_kernel<<<BB * (NTOK / 64), 256, 0, stream>>>(Qhw, Qlw, K1w, K2w, Vtw, qry, mu, out);
}